// Round 1
// baseline (492.781 us; speedup 1.0000x reference)
//
#include <hip/hip_runtime.h>
#include <cstdint>

#define NB 2
#define NN 1024
#define MM 2048
#define DD 512
#define HH 64

// ---------------- left = U@Wl, right = U@Wr : (2048,512)x(512,64) ----------------
__global__ __launch_bounds__(256) void lr_kernel(
    const float* __restrict__ U, const float* __restrict__ Wl,
    const float* __restrict__ Wr, float* __restrict__ left,
    float* __restrict__ right) {
  __shared__ float u[8][DD];                 // 8 rows staged, 16 KB
  const int block = blockIdx.x;              // 256 blocks x 8 rows
  const int tid = threadIdx.x;
  const float4* Uv = (const float4*)(U + (size_t)block * 8 * DD);
  float4* uv = (float4*)&u[0][0];
#pragma unroll
  for (int t = 0; t < 4; ++t) uv[tid + t * 256] = Uv[tid + t * 256];
  __syncthreads();
  const int h = tid & 63;
  const int isR = (tid >> 6) & 1;
  const int rbase = tid >> 7;                // 0 or 1
  const float* __restrict__ W = isR ? Wr : Wl;
  float acc[4] = {0.f, 0.f, 0.f, 0.f};
  for (int k0 = 0; k0 < DD; k0 += 4) {
    float w0 = W[(k0 + 0) * HH + h];
    float w1 = W[(k0 + 1) * HH + h];
    float w2 = W[(k0 + 2) * HH + h];
    float w3 = W[(k0 + 3) * HH + h];
#pragma unroll
    for (int r = 0; r < 4; ++r) {
      float4 u4 = *(const float4*)&u[rbase + r * 2][k0];
      acc[r] = fmaf(u4.w, w3, fmaf(u4.z, w2, fmaf(u4.y, w1, fmaf(u4.x, w0, acc[r]))));
    }
  }
  float* out = isR ? right : left;
#pragma unroll
  for (int r = 0; r < 4; ++r)
    out[(size_t)(block * 8 + rbase + r * 2) * HH + h] = acc[r];
}

// ------------- scores + softmax -> probs. One block per (b,i) row. -------------
__global__ __launch_bounds__(256) void score_kernel(
    const float* __restrict__ left, const float* __restrict__ right,
    const int* __restrict__ span_begin, const float* __restrict__ mask,
    const float* __restrict__ dist_emb, const float* __restrict__ b_h,
    const float* __restrict__ v_out, float* __restrict__ probs) {
  const int row = blockIdx.x;                // b*NN + i
  const int b = row >> 10;
  const int tid = threadIdx.x;
  __shared__ float Ld[10][68];               // left_i + b_h + dist_emb[bk], padded stride
  __shared__ int sbl[NN];
  __shared__ float redm[4], reds[4];
  for (int t = tid; t < 640; t += 256) {
    int bk = t >> 6, h = t & 63;
    Ld[bk][h] = dist_emb[t] + left[(size_t)row * HH + h] + b_h[h];
  }
  for (int t = tid; t < NN; t += 256) sbl[t] = span_begin[b * NN + t];
  float4 vr[16];
  const float4* v4g = (const float4*)v_out;
#pragma unroll
  for (int hq = 0; hq < 16; ++hq) vr[hq] = v4g[hq];
  __syncthreads();
  const int sbi = span_begin[row];
  const float4* R4 = (const float4*)(right + (size_t)b * NN * HH);
  float s[4];
#pragma unroll
  for (int q = 0; q < 4; ++q) {
    const int j = (q << 8) + tid;
    int dd = sbl[j] - sbi; dd = dd < 0 ? -dd : dd;
    const int bk = dd <= 4 ? dd : (dd <= 7 ? 5 : (dd <= 15 ? 6 : (dd <= 31 ? 7 : (dd <= 63 ? 8 : 9))));
    const float4* ldp = (const float4*)&Ld[bk][0];
    const float4* rp = R4 + (size_t)j * 16;
    float acc = 0.f;
#pragma unroll
    for (int hq = 0; hq < 16; ++hq) {
      float4 z = ldp[hq];
      float4 r4 = rp[hq];
      float x0 = z.x + r4.x; x0 = x0 > 0.f ? x0 : 0.f;
      float x1 = z.y + r4.y; x1 = x1 > 0.f ? x1 : 0.f;
      float x2 = z.z + r4.z; x2 = x2 > 0.f ? x2 : 0.f;
      float x3 = z.w + r4.w; x3 = x3 > 0.f ? x3 : 0.f;
      acc = fmaf(x0, vr[hq].x, acc);
      acc = fmaf(x1, vr[hq].y, acc);
      acc = fmaf(x2, vr[hq].z, acc);
      acc = fmaf(x3, vr[hq].w, acc);
    }
    const float mval = mask[(size_t)row * NN + j];
    s[q] = acc - (1.0f - mval) * 1e23f;      // b_out omitted: cancels in softmax
  }
  float mx = fmaxf(fmaxf(s[0], s[1]), fmaxf(s[2], s[3]));
#pragma unroll
  for (int off = 32; off; off >>= 1) mx = fmaxf(mx, __shfl_down(mx, off));
  const int wv = tid >> 6;
  if ((tid & 63) == 0) redm[wv] = mx;
  __syncthreads();
  mx = fmaxf(fmaxf(redm[0], redm[1]), fmaxf(redm[2], redm[3]));
  float e[4], sum = 0.f;
#pragma unroll
  for (int q = 0; q < 4; ++q) { e[q] = __expf(s[q] - mx); sum += e[q]; }
#pragma unroll
  for (int off = 32; off; off >>= 1) sum += __shfl_down(sum, off);
  if ((tid & 63) == 0) reds[wv] = sum;
  __syncthreads();
  sum = reds[0] + reds[1] + reds[2] + reds[3];
  const float inv = 1.0f / sum;
#pragma unroll
  for (int q = 0; q < 4; ++q)
    probs[(size_t)row * NN + (q << 8) + tid] = e[q] * inv;
}

// ---------------- ctxt = P @ U : per batch (1024x1024)x(1024x512) ----------------
__global__ __launch_bounds__(256) void gemm_ctxt(
    const float* __restrict__ P, const float* __restrict__ U,
    float* __restrict__ C) {
  __shared__ float At[32][68];               // A tile transposed: [k][row]
  __shared__ float Bt[32][68];               // [k][col]
  const int b = blockIdx.z;
  const int i0 = blockIdx.y * 64, d0 = blockIdx.x * 64;
  const int tid = threadIdx.x;
  const int tx = tid & 15, ty = tid >> 4;
  const float* __restrict__ Pb = P + (size_t)b * NN * NN;
  const float* __restrict__ Ub = U + (size_t)b * NN * DD;
  float acc[4][4] = {};
  for (int k0 = 0; k0 < NN; k0 += 32) {
#pragma unroll
    for (int t = 0; t < 2; ++t) {
      int idx = tid + t * 256;
      int r = idx >> 3, c4 = idx & 7;
      float4 v = *(const float4*)&Pb[(size_t)(i0 + r) * NN + k0 + c4 * 4];
      At[c4 * 4 + 0][r] = v.x; At[c4 * 4 + 1][r] = v.y;
      At[c4 * 4 + 2][r] = v.z; At[c4 * 4 + 3][r] = v.w;
    }
#pragma unroll
    for (int t = 0; t < 2; ++t) {
      int idx = tid + t * 256;
      int r = idx >> 4, c4 = idx & 15;
      *(float4*)&Bt[r][c4 * 4] = *(const float4*)&Ub[(size_t)(k0 + r) * DD + d0 + c4 * 4];
    }
    __syncthreads();
#pragma unroll
    for (int k = 0; k < 32; ++k) {
      const float4 av = *(const float4*)&At[k][ty * 4];
      const float4 bv = *(const float4*)&Bt[k][tx * 4];
      const float a[4] = {av.x, av.y, av.z, av.w};
      const float bb[4] = {bv.x, bv.y, bv.z, bv.w};
#pragma unroll
      for (int r = 0; r < 4; ++r)
#pragma unroll
        for (int c = 0; c < 4; ++c)
          acc[r][c] = fmaf(a[r], bb[c], acc[r][c]);
    }
    __syncthreads();
  }
#pragma unroll
  for (int r = 0; r < 4; ++r) {
    float4 o; o.x = acc[r][0]; o.y = acc[r][1]; o.z = acc[r][2]; o.w = acc[r][3];
    *(float4*)&C[(size_t)b * NN * DD + (size_t)(i0 + ty * 4 + r) * DD + d0 + tx * 4] = o;
  }
}

// --------- gate GEMM: [U|C](2048x1024) @ Wg(1024x512) + sigmoid + blend ---------
__global__ __launch_bounds__(256) void gemm_gate(
    const float* __restrict__ U, const float* __restrict__ Cin,
    const float* __restrict__ Wg, const float* __restrict__ bg,
    float* __restrict__ Uout) {
  __shared__ float At[32][68];
  __shared__ float Bt[32][68];
  const int b = blockIdx.z;
  const int i0 = blockIdx.y * 64, d0 = blockIdx.x * 64;
  const int tid = threadIdx.x;
  const int tx = tid & 15, ty = tid >> 4;
  const float* __restrict__ Ub = U + (size_t)b * NN * DD;
  const float* __restrict__ Cb = Cin + (size_t)b * NN * DD;
  float acc[4][4] = {};
  for (int k0 = 0; k0 < 2 * DD; k0 += 32) {
    const float* __restrict__ src = (k0 < DD) ? Ub : Cb;  // concat([U, C], -1)
    const int kc = k0 & (DD - 1);
#pragma unroll
    for (int t = 0; t < 2; ++t) {
      int idx = tid + t * 256;
      int r = idx >> 3, c4 = idx & 7;
      float4 v = *(const float4*)&src[(size_t)(i0 + r) * DD + kc + c4 * 4];
      At[c4 * 4 + 0][r] = v.x; At[c4 * 4 + 1][r] = v.y;
      At[c4 * 4 + 2][r] = v.z; At[c4 * 4 + 3][r] = v.w;
    }
#pragma unroll
    for (int t = 0; t < 2; ++t) {
      int idx = tid + t * 256;
      int r = idx >> 4, c4 = idx & 15;
      *(float4*)&Bt[r][c4 * 4] = *(const float4*)&Wg[(size_t)(k0 + r) * DD + d0 + c4 * 4];
    }
    __syncthreads();
#pragma unroll
    for (int k = 0; k < 32; ++k) {
      const float4 av = *(const float4*)&At[k][ty * 4];
      const float4 bv = *(const float4*)&Bt[k][tx * 4];
      const float a[4] = {av.x, av.y, av.z, av.w};
      const float bb[4] = {bv.x, bv.y, bv.z, bv.w};
#pragma unroll
      for (int r = 0; r < 4; ++r)
#pragma unroll
        for (int c = 0; c < 4; ++c)
          acc[r][c] = fmaf(a[r], bb[c], acc[r][c]);
    }
    __syncthreads();
  }
  const float4 bg4 = *(const float4*)&bg[d0 + tx * 4];
#pragma unroll
  for (int r = 0; r < 4; ++r) {
    const size_t off = (size_t)(i0 + ty * 4 + r) * DD + d0 + tx * 4;
    const float4 uv = *(const float4*)&Ub[off];
    const float4 cv = *(const float4*)&Cb[off];
    const float g0 = 1.f / (1.f + __expf(-(acc[r][0] + bg4.x)));
    const float g1 = 1.f / (1.f + __expf(-(acc[r][1] + bg4.y)));
    const float g2 = 1.f / (1.f + __expf(-(acc[r][2] + bg4.z)));
    const float g3 = 1.f / (1.f + __expf(-(acc[r][3] + bg4.w)));
    float4 o;
    o.x = g0 * uv.x + (1.f - g0) * cv.x;
    o.y = g1 * uv.y + (1.f - g1) * cv.y;
    o.z = g2 * uv.z + (1.f - g2) * cv.z;
    o.w = g3 * uv.w + (1.f - g3) * cv.w;
    *(float4*)&Uout[(size_t)b * NN * DD + off] = o;
  }
}

// --------- output assembly: out = [cand copy | final update copy] ----------
__global__ __launch_bounds__(256) void out_copy(
    const float* __restrict__ cand, const float* __restrict__ upd,
    float* __restrict__ out) {
  const int t = blockIdx.x * 256 + threadIdx.x;   // float4 index, 786432 total
  float4* o4 = (float4*)out;
  if (t < 524288) o4[t] = ((const float4*)cand)[t];
  else o4[t] = ((const float4*)upd)[t - 524288];
}

// --------- scatter: cand_new[b, prune[b,i], :] = upd[b,i,:] for i < span_len[b] ---------
__global__ __launch_bounds__(128) void scatter_k(
    float* __restrict__ out_cand, const float* __restrict__ upd,
    const int* __restrict__ prune, const int* __restrict__ span_len) {
  const int row = blockIdx.x;                // b*NN + i
  const int b = row >> 10, i = row & 1023;
  if (i >= span_len[b]) return;              // masked rows: no-op (unique indices)
  const int dst = prune[row];
  const float4* src = (const float4*)(upd + (size_t)row * DD);
  float4* d = (float4*)(out_cand + ((size_t)b * MM + dst) * DD);
  d[threadIdx.x] = src[threadIdx.x];
}

extern "C" void kernel_launch(void* const* d_in, const int* in_sizes, int n_in,
                              void* d_out, int out_size, void* d_ws, size_t ws_size,
                              hipStream_t stream) {
  const float* update = (const float*)d_in[0];
  const float* mask = (const float*)d_in[1];
  const float* cand = (const float*)d_in[2];
  const int* span_begin = (const int*)d_in[3];
  // d_in[4] span_end: unused by reference
  const int* prune = (const int*)d_in[5];
  const int* span_len = (const int*)d_in[6];
  const float* Wl = (const float*)d_in[7];
  const float* Wr = (const float*)d_in[8];
  const float* b_h = (const float*)d_in[9];
  const float* dist_emb = (const float*)d_in[10];
  const float* v_out = (const float*)d_in[11];
  // d_in[12] b_out: constant shift, cancels in softmax
  const float* Wg = (const float*)d_in[13];
  const float* b_gate = (const float*)d_in[14];

  // workspace layout (floats): ~21 MB total, all rewritten every launch
  float* ws = (float*)d_ws;
  float* left = ws;                                    // 131072
  float* right = left + (size_t)NB * NN * HH;          // 131072
  float* probs = right + (size_t)NB * NN * HH;         // 2097152
  float* ctxt = probs + (size_t)NB * NN * NN;          // 1048576
  float* upd1 = ctxt + (size_t)NB * NN * DD;           // 1048576
  float* upd2 = upd1 + (size_t)NB * NN * DD;           // 1048576

  float* out = (float*)d_out;

  const float* Ucur = update;
  float* nexts[2] = {upd1, upd2};
  for (int it = 0; it < 2; ++it) {
    lr_kernel<<<256, 256, 0, stream>>>(Ucur, Wl, Wr, left, right);
    score_kernel<<<NB * NN, 256, 0, stream>>>(left, right, span_begin, mask,
                                              dist_emb, b_h, v_out, probs);
    gemm_ctxt<<<dim3(8, 16, NB), 256, 0, stream>>>(probs, Ucur, ctxt);
    gemm_gate<<<dim3(8, 16, NB), 256, 0, stream>>>(Ucur, ctxt, Wg, b_gate, nexts[it]);
    Ucur = nexts[it];
  }
  out_copy<<<3072, 256, 0, stream>>>(cand, Ucur, out);
  scatter_k<<<NB * NN, 128, 0, stream>>>(out, Ucur, prune, span_len);
}

// Round 2
// 384.347 us; speedup vs baseline: 1.2821x; 1.2821x over previous
//
#include <hip/hip_runtime.h>
#include <cstdint>

#define NB 2
#define NN 1024
#define MM 2048
#define DD 512
#define HH 64
#define IT 16          // i-tile of score_compute
#define JT 64          // j-tile of score_compute
#define ST 68          // padded LDS stride (uniform bank spread for b128)

// ---------------- left = U@Wl, right = U@Wr : (2048,512)x(512,64) ----------------
__global__ __launch_bounds__(256) void lr_kernel(
    const float* __restrict__ U, const float* __restrict__ Wl,
    const float* __restrict__ Wr, float* __restrict__ left,
    float* __restrict__ right) {
  __shared__ float u[8][DD];                 // 8 rows staged, 16 KB
  const int block = blockIdx.x;              // 256 blocks x 8 rows
  const int tid = threadIdx.x;
  const float4* Uv = (const float4*)(U + (size_t)block * 8 * DD);
  float4* uv = (float4*)&u[0][0];
#pragma unroll
  for (int t = 0; t < 4; ++t) uv[tid + t * 256] = Uv[tid + t * 256];
  __syncthreads();
  const int h = tid & 63;
  const int isR = (tid >> 6) & 1;
  const int rbase = tid >> 7;                // 0 or 1
  const float* __restrict__ W = isR ? Wr : Wl;
  float acc[4] = {0.f, 0.f, 0.f, 0.f};
  for (int k0 = 0; k0 < DD; k0 += 4) {
    float w0 = W[(k0 + 0) * HH + h];
    float w1 = W[(k0 + 1) * HH + h];
    float w2 = W[(k0 + 2) * HH + h];
    float w3 = W[(k0 + 3) * HH + h];
#pragma unroll
    for (int r = 0; r < 4; ++r) {
      float4 u4 = *(const float4*)&u[rbase + r * 2][k0];
      acc[r] = fmaf(u4.w, w3, fmaf(u4.z, w2, fmaf(u4.y, w1, fmaf(u4.x, w0, acc[r]))));
    }
  }
  float* out = isR ? right : left;
#pragma unroll
  for (int r = 0; r < 4; ++r)
    out[(size_t)(block * 8 + rbase + r * 2) * HH + h] = acc[r];
}

// ---------- score_compute: raw biased scores for a 16x64 (i,j) tile ----------
// scores(i,j) = sum_h relu(left[i,h]+right[j,h]+dist[bk(i,j),h]+b_h[h]) * v[h]
//              - (1-mask)*1e23      (b_out omitted: cancels in softmax)
__global__ __launch_bounds__(256) void score_compute(
    const float* __restrict__ left, const float* __restrict__ right,
    const int* __restrict__ span_begin, const float* __restrict__ mask,
    const float* __restrict__ dist_emb, const float* __restrict__ b_h,
    const float* __restrict__ v_out, float* __restrict__ scores) {
  __shared__ float Rt[JT][ST];         // right tile        17408 B
  __shared__ float LDb[IT * 10][ST];   // left+dist+b_h     43520 B
  __shared__ float Lt[IT][ST];         // left tile          4352 B
  __shared__ float Dbh[10][ST];        // dist+b_h           2720 B
  __shared__ float Vl[ST];             // v_out
  __shared__ int sbi[IT];
  __shared__ int sbj[JT];
  const int b = blockIdx.z;
  const int i0 = blockIdx.y * IT;
  const int j0 = blockIdx.x * JT;
  const int tid = threadIdx.x;

  // stage right tile: 64 rows x 16 float4, coalesced
  for (int f = tid; f < JT * 16; f += 256) {
    int r = f >> 4, h4 = f & 15;
    *(float4*)&Rt[r][h4 * 4] =
        *(const float4*)&right[((size_t)b * NN + j0 + r) * HH + h4 * 4];
  }
  // stage left tile: 16 rows x 16 float4
  {
    int r = tid >> 4, h4 = tid & 15;
    *(float4*)&Lt[r][h4 * 4] =
        *(const float4*)&left[((size_t)b * NN + i0 + r) * HH + h4 * 4];
  }
  // stage dist_emb + b_h
  for (int f = tid; f < 160; f += 256) {
    int bk = f >> 4, h4 = f & 15;
    float4 d = *(const float4*)&dist_emb[bk * HH + h4 * 4];
    float4 bh = *(const float4*)&b_h[h4 * 4];
    d.x += bh.x; d.y += bh.y; d.z += bh.z; d.w += bh.w;
    *(float4*)&Dbh[bk][h4 * 4] = d;
  }
  if (tid < 16) *(float4*)&Vl[tid * 4] = *(const float4*)&v_out[tid * 4];
  if (tid >= 64 && tid < 64 + IT) sbi[tid - 64] = span_begin[b * NN + i0 + tid - 64];
  if (tid >= 128 && tid < 128 + JT) sbj[tid - 128] = span_begin[b * NN + j0 + tid - 128];
  __syncthreads();
  // LDb[i*10+bk] = Lt[i] + Dbh[bk]
  {
    const int i = tid >> 4, h4 = tid & 15;
    const float4 l4 = *(const float4*)&Lt[i][h4 * 4];
#pragma unroll
    for (int bk = 0; bk < 10; ++bk) {
      float4 d = *(const float4*)&Dbh[bk][h4 * 4];
      d.x += l4.x; d.y += l4.y; d.z += l4.z; d.w += l4.w;
      *(float4*)&LDb[i * 10 + bk][h4 * 4] = d;
    }
  }
  __syncthreads();

  const int i = tid >> 4, jq = tid & 15;
  const float* LDbF = &LDb[0][0];
  const int my_sbi = sbi[i];
  int rowL[4];
#pragma unroll
  for (int jj = 0; jj < 4; ++jj) {
    const int jl = jq * 4 + jj;
    int d = sbj[jl] - my_sbi;
    d = d < 0 ? -d : d;
    const int bk =
        d <= 4 ? d : (d <= 7 ? 5 : (d <= 15 ? 6 : (d <= 31 ? 7 : (d <= 63 ? 8 : 9))));
    rowL[jj] = (i * 10 + bk) * ST;
  }
  float acc[4] = {0.f, 0.f, 0.f, 0.f};
#pragma unroll
  for (int hq = 0; hq < 16; ++hq) {
    const float4 v4 = *(const float4*)&Vl[hq * 4];
#pragma unroll
    for (int jj = 0; jj < 4; ++jj) {
      const float4 z = *(const float4*)&LDbF[rowL[jj] + hq * 4];
      const float4 r4 = *(const float4*)&Rt[jq * 4 + jj][hq * 4];
      float x0 = fmaxf(z.x + r4.x, 0.f);
      float x1 = fmaxf(z.y + r4.y, 0.f);
      float x2 = fmaxf(z.z + r4.z, 0.f);
      float x3 = fmaxf(z.w + r4.w, 0.f);
      acc[jj] = fmaf(x0, v4.x, acc[jj]);
      acc[jj] = fmaf(x1, v4.y, acc[jj]);
      acc[jj] = fmaf(x2, v4.z, acc[jj]);
      acc[jj] = fmaf(x3, v4.w, acc[jj]);
    }
  }
  const size_t rowoff = ((size_t)b * NN + i0 + i) * NN + j0 + jq * 4;
  const float4 m4 = *(const float4*)&mask[rowoff];
  float4 s4;
  s4.x = acc[0] - (1.0f - m4.x) * 1e23f;
  s4.y = acc[1] - (1.0f - m4.y) * 1e23f;
  s4.z = acc[2] - (1.0f - m4.z) * 1e23f;
  s4.w = acc[3] - (1.0f - m4.w) * 1e23f;
  *(float4*)&scores[rowoff] = s4;
}

// ---------- softmax_k: in-place row softmax, one wave per row ----------
__global__ __launch_bounds__(256) void softmax_k(float* __restrict__ scores) {
  const int wave = threadIdx.x >> 6, lane = threadIdx.x & 63;
  const int row = blockIdx.x * 4 + wave;
  float4* p = (float4*)(scores + (size_t)row * NN);
  float4 v[4];
  float mx = -3.0e38f;
#pragma unroll
  for (int q = 0; q < 4; ++q) {
    v[q] = p[lane + q * 64];
    mx = fmaxf(mx, fmaxf(fmaxf(v[q].x, v[q].y), fmaxf(v[q].z, v[q].w)));
  }
#pragma unroll
  for (int off = 32; off; off >>= 1) mx = fmaxf(mx, __shfl_xor(mx, off));
  float sum = 0.f;
#pragma unroll
  for (int q = 0; q < 4; ++q) {
    v[q].x = __expf(v[q].x - mx); v[q].y = __expf(v[q].y - mx);
    v[q].z = __expf(v[q].z - mx); v[q].w = __expf(v[q].w - mx);
    sum += v[q].x + v[q].y + v[q].z + v[q].w;
  }
#pragma unroll
  for (int off = 32; off; off >>= 1) sum += __shfl_xor(sum, off);
  const float inv = 1.0f / sum;
#pragma unroll
  for (int q = 0; q < 4; ++q) {
    v[q].x *= inv; v[q].y *= inv; v[q].z *= inv; v[q].w *= inv;
    p[lane + q * 64] = v[q];
  }
}

// ---------------- ctxt = P @ U : per batch (1024x1024)x(1024x512) ----------------
__global__ __launch_bounds__(256) void gemm_ctxt(
    const float* __restrict__ P, const float* __restrict__ U,
    float* __restrict__ C) {
  __shared__ float At[32][68];               // A tile transposed: [k][row]
  __shared__ float Bt[32][68];               // [k][col]
  const int b = blockIdx.z;
  const int i0 = blockIdx.y * 64, d0 = blockIdx.x * 64;
  const int tid = threadIdx.x;
  const int tx = tid & 15, ty = tid >> 4;
  const float* __restrict__ Pb = P + (size_t)b * NN * NN;
  const float* __restrict__ Ub = U + (size_t)b * NN * DD;
  float acc[4][4] = {};
  for (int k0 = 0; k0 < NN; k0 += 32) {
#pragma unroll
    for (int t = 0; t < 2; ++t) {
      int idx = tid + t * 256;
      int r = idx >> 3, c4 = idx & 7;
      float4 v = *(const float4*)&Pb[(size_t)(i0 + r) * NN + k0 + c4 * 4];
      At[c4 * 4 + 0][r] = v.x; At[c4 * 4 + 1][r] = v.y;
      At[c4 * 4 + 2][r] = v.z; At[c4 * 4 + 3][r] = v.w;
    }
#pragma unroll
    for (int t = 0; t < 2; ++t) {
      int idx = tid + t * 256;
      int r = idx >> 4, c4 = idx & 15;
      *(float4*)&Bt[r][c4 * 4] = *(const float4*)&Ub[(size_t)(k0 + r) * DD + d0 + c4 * 4];
    }
    __syncthreads();
#pragma unroll
    for (int k = 0; k < 32; ++k) {
      const float4 av = *(const float4*)&At[k][ty * 4];
      const float4 bv = *(const float4*)&Bt[k][tx * 4];
      const float a[4] = {av.x, av.y, av.z, av.w};
      const float bb[4] = {bv.x, bv.y, bv.z, bv.w};
#pragma unroll
      for (int r = 0; r < 4; ++r)
#pragma unroll
        for (int c = 0; c < 4; ++c)
          acc[r][c] = fmaf(a[r], bb[c], acc[r][c]);
    }
    __syncthreads();
  }
#pragma unroll
  for (int r = 0; r < 4; ++r) {
    float4 o; o.x = acc[r][0]; o.y = acc[r][1]; o.z = acc[r][2]; o.w = acc[r][3];
    *(float4*)&C[(size_t)b * NN * DD + (size_t)(i0 + ty * 4 + r) * DD + d0 + tx * 4] = o;
  }
}

// --------- gate GEMM: [U|C](2048x1024) @ Wg(1024x512) + sigmoid + blend ---------
__global__ __launch_bounds__(256) void gemm_gate(
    const float* __restrict__ U, const float* __restrict__ Cin,
    const float* __restrict__ Wg, const float* __restrict__ bg,
    float* __restrict__ Uout) {
  __shared__ float At[32][68];
  __shared__ float Bt[32][68];
  const int b = blockIdx.z;
  const int i0 = blockIdx.y * 64, d0 = blockIdx.x * 64;
  const int tid = threadIdx.x;
  const int tx = tid & 15, ty = tid >> 4;
  const float* __restrict__ Ub = U + (size_t)b * NN * DD;
  const float* __restrict__ Cb = Cin + (size_t)b * NN * DD;
  float acc[4][4] = {};
  for (int k0 = 0; k0 < 2 * DD; k0 += 32) {
    const float* __restrict__ src = (k0 < DD) ? Ub : Cb;  // concat([U, C], -1)
    const int kc = k0 & (DD - 1);
#pragma unroll
    for (int t = 0; t < 2; ++t) {
      int idx = tid + t * 256;
      int r = idx >> 3, c4 = idx & 7;
      float4 v = *(const float4*)&src[(size_t)(i0 + r) * DD + kc + c4 * 4];
      At[c4 * 4 + 0][r] = v.x; At[c4 * 4 + 1][r] = v.y;
      At[c4 * 4 + 2][r] = v.z; At[c4 * 4 + 3][r] = v.w;
    }
#pragma unroll
    for (int t = 0; t < 2; ++t) {
      int idx = tid + t * 256;
      int r = idx >> 4, c4 = idx & 15;
      *(float4*)&Bt[r][c4 * 4] = *(const float4*)&Wg[(size_t)(k0 + r) * DD + d0 + c4 * 4];
    }
    __syncthreads();
#pragma unroll
    for (int k = 0; k < 32; ++k) {
      const float4 av = *(const float4*)&At[k][ty * 4];
      const float4 bv = *(const float4*)&Bt[k][tx * 4];
      const float a[4] = {av.x, av.y, av.z, av.w};
      const float bb[4] = {bv.x, bv.y, bv.z, bv.w};
#pragma unroll
      for (int r = 0; r < 4; ++r)
#pragma unroll
        for (int c = 0; c < 4; ++c)
          acc[r][c] = fmaf(a[r], bb[c], acc[r][c]);
    }
    __syncthreads();
  }
  const float4 bg4 = *(const float4*)&bg[d0 + tx * 4];
#pragma unroll
  for (int r = 0; r < 4; ++r) {
    const size_t off = (size_t)(i0 + ty * 4 + r) * DD + d0 + tx * 4;
    const float4 uv = *(const float4*)&Ub[off];
    const float4 cv = *(const float4*)&Cb[off];
    const float g0 = 1.f / (1.f + __expf(-(acc[r][0] + bg4.x)));
    const float g1 = 1.f / (1.f + __expf(-(acc[r][1] + bg4.y)));
    const float g2 = 1.f / (1.f + __expf(-(acc[r][2] + bg4.z)));
    const float g3 = 1.f / (1.f + __expf(-(acc[r][3] + bg4.w)));
    float4 o;
    o.x = g0 * uv.x + (1.f - g0) * cv.x;
    o.y = g1 * uv.y + (1.f - g1) * cv.y;
    o.z = g2 * uv.z + (1.f - g2) * cv.z;
    o.w = g3 * uv.w + (1.f - g3) * cv.w;
    *(float4*)&Uout[(size_t)b * NN * DD + off] = o;
  }
}

// --------- output assembly: out = [cand copy | final update copy] ----------
__global__ __launch_bounds__(256) void out_copy(
    const float* __restrict__ cand, const float* __restrict__ upd,
    float* __restrict__ out) {
  const int t = blockIdx.x * 256 + threadIdx.x;   // float4 index, 786432 total
  float4* o4 = (float4*)out;
  if (t < 524288) o4[t] = ((const float4*)cand)[t];
  else o4[t] = ((const float4*)upd)[t - 524288];
}

// --------- scatter: cand_new[b, prune[b,i], :] = upd[b,i,:] for i < span_len[b] ---------
__global__ __launch_bounds__(128) void scatter_k(
    float* __restrict__ out_cand, const float* __restrict__ upd,
    const int* __restrict__ prune, const int* __restrict__ span_len) {
  const int row = blockIdx.x;                // b*NN + i
  const int b = row >> 10, i = row & 1023;
  if (i >= span_len[b]) return;              // masked rows: no-op (unique indices)
  const int dst = prune[row];
  const float4* src = (const float4*)(upd + (size_t)row * DD);
  float4* d = (float4*)(out_cand + ((size_t)b * MM + dst) * DD);
  d[threadIdx.x] = src[threadIdx.x];
}

extern "C" void kernel_launch(void* const* d_in, const int* in_sizes, int n_in,
                              void* d_out, int out_size, void* d_ws, size_t ws_size,
                              hipStream_t stream) {
  const float* update = (const float*)d_in[0];
  const float* mask = (const float*)d_in[1];
  const float* cand = (const float*)d_in[2];
  const int* span_begin = (const int*)d_in[3];
  // d_in[4] span_end: unused by reference
  const int* prune = (const int*)d_in[5];
  const int* span_len = (const int*)d_in[6];
  const float* Wl = (const float*)d_in[7];
  const float* Wr = (const float*)d_in[8];
  const float* b_h = (const float*)d_in[9];
  const float* dist_emb = (const float*)d_in[10];
  const float* v_out = (const float*)d_in[11];
  // d_in[12] b_out: constant shift, cancels in softmax
  const float* Wg = (const float*)d_in[13];
  const float* b_gate = (const float*)d_in[14];

  // workspace layout (floats): ~21 MB total, all rewritten every launch
  float* ws = (float*)d_ws;
  float* left = ws;                                    // 131072
  float* right = left + (size_t)NB * NN * HH;          // 131072
  float* probs = right + (size_t)NB * NN * HH;         // 2097152 (scores in-place)
  float* ctxt = probs + (size_t)NB * NN * NN;          // 1048576
  float* upd1 = ctxt + (size_t)NB * NN * DD;           // 1048576
  float* upd2 = upd1 + (size_t)NB * NN * DD;           // 1048576

  float* out = (float*)d_out;

  const float* Ucur = update;
  float* nexts[2] = {upd1, upd2};
  for (int it = 0; it < 2; ++it) {
    lr_kernel<<<256, 256, 0, stream>>>(Ucur, Wl, Wr, left, right);
    score_compute<<<dim3(NN / JT, NN / IT, NB), 256, 0, stream>>>(
        left, right, span_begin, mask, dist_emb, b_h, v_out, probs);
    softmax_k<<<NB * NN / 4, 256, 0, stream>>>(probs);
    gemm_ctxt<<<dim3(8, 16, NB), 256, 0, stream>>>(probs, Ucur, ctxt);
    gemm_gate<<<dim3(8, 16, NB), 256, 0, stream>>>(Ucur, ctxt, Wg, b_gate, nexts[it]);
    Ucur = nexts[it];
  }
  out_copy<<<3072, 256, 0, stream>>>(cand, Ucur, out);
  scatter_k<<<NB * NN, 128, 0, stream>>>(out, Ucur, prune, span_len);
}

// Round 3
// 260.846 us; speedup vs baseline: 1.8892x; 1.4735x over previous
//
#include <hip/hip_runtime.h>
#include <cstdint>

#define NB 2
#define NN 1024
#define MM 2048
#define DD 512
#define HH 64
#define IT 16          // i-tile of score_compute
#define JT 64          // j-tile of score_compute
#define ST 68          // padded LDS stride

typedef __attribute__((ext_vector_type(8))) short bf16x8;
typedef __attribute__((ext_vector_type(4))) float f32x4;

__device__ inline ushort f2bf(float x) {
  union { float f; uint32_t u; } v; v.f = x;
  uint32_t u = v.u;
  u += 0x7FFF + ((u >> 16) & 1);      // RNE
  return (ushort)(u >> 16);
}

#define GLDS(gp, lp) \
  __builtin_amdgcn_global_load_lds( \
      (const __attribute__((address_space(1))) void*)(gp), \
      (__attribute__((address_space(3))) void*)(lp), 16, 0, 0)

// ---------------- left = U@Wl, right = U@Wr : (2048,512)x(512,64) ----------------
__global__ __launch_bounds__(256) void lr_kernel(
    const float* __restrict__ U, const float* __restrict__ Wl,
    const float* __restrict__ Wr, float* __restrict__ left,
    float* __restrict__ right) {
  __shared__ float u[8][DD];
  const int block = blockIdx.x;
  const int tid = threadIdx.x;
  const float4* Uv = (const float4*)(U + (size_t)block * 8 * DD);
  float4* uv = (float4*)&u[0][0];
#pragma unroll
  for (int t = 0; t < 4; ++t) uv[tid + t * 256] = Uv[tid + t * 256];
  __syncthreads();
  const int h = tid & 63;
  const int isR = (tid >> 6) & 1;
  const int rbase = tid >> 7;
  const float* __restrict__ W = isR ? Wr : Wl;
  float acc[4] = {0.f, 0.f, 0.f, 0.f};
  for (int k0 = 0; k0 < DD; k0 += 4) {
    float w0 = W[(k0 + 0) * HH + h];
    float w1 = W[(k0 + 1) * HH + h];
    float w2 = W[(k0 + 2) * HH + h];
    float w3 = W[(k0 + 3) * HH + h];
#pragma unroll
    for (int r = 0; r < 4; ++r) {
      float4 u4 = *(const float4*)&u[rbase + r * 2][k0];
      acc[r] = fmaf(u4.w, w3, fmaf(u4.z, w2, fmaf(u4.y, w1, fmaf(u4.x, w0, acc[r]))));
    }
  }
  float* out = isR ? right : left;
#pragma unroll
  for (int r = 0; r < 4; ++r)
    out[(size_t)(block * 8 + rbase + r * 2) * HH + h] = acc[r];
}

// ------- conv_t: fp32 [R][C] -> optional bf16 row-major + bf16 transposed [C][R] -------
__global__ __launch_bounds__(256) void conv_t(
    const float* __restrict__ in, ushort* __restrict__ out_row,
    ushort* __restrict__ out_T, int R, int C, int write_row) {
  __shared__ float tile[64][65];
  const int b = blockIdx.z;
  const int r0 = blockIdx.y * 64, c0 = blockIdx.x * 64;
  const int tx = threadIdx.x & 15, ty = threadIdx.x >> 4;
  const float* inb = in + (size_t)b * R * C;
#pragma unroll
  for (int p = 0; p < 4; ++p) {
    const int r = ty + p * 16;
    const float4 v = *(const float4*)&inb[(size_t)(r0 + r) * C + c0 + tx * 4];
    tile[r][tx * 4 + 0] = v.x; tile[r][tx * 4 + 1] = v.y;
    tile[r][tx * 4 + 2] = v.z; tile[r][tx * 4 + 3] = v.w;
    if (write_row) {
      ushort4 o = make_ushort4(f2bf(v.x), f2bf(v.y), f2bf(v.z), f2bf(v.w));
      *(ushort4*)&out_row[(size_t)b * R * C + (size_t)(r0 + r) * C + c0 + tx * 4] = o;
    }
  }
  __syncthreads();
  ushort* oT = out_T + (size_t)b * R * C;
#pragma unroll
  for (int p = 0; p < 4; ++p) {
    const int rr = ty + p * 16;     // row of out_T = col c0+rr of in
    ushort4 o;
    o.x = f2bf(tile[tx * 4 + 0][rr]);
    o.y = f2bf(tile[tx * 4 + 1][rr]);
    o.z = f2bf(tile[tx * 4 + 2][rr]);
    o.w = f2bf(tile[tx * 4 + 3][rr]);
    *(ushort4*)&oT[(size_t)(c0 + rr) * R + r0 + tx * 4] = o;
  }
}

// ---------- score_compute: raw biased scores for a 16x64 (i,j) tile ----------
__global__ __launch_bounds__(256) void score_compute(
    const float* __restrict__ left, const float* __restrict__ right,
    const int* __restrict__ span_begin, const float* __restrict__ mask,
    const float* __restrict__ dist_emb, const float* __restrict__ b_h,
    const float* __restrict__ v_out, float* __restrict__ scores) {
  __shared__ float Rt[JT][ST];
  __shared__ float LDb[IT * 10][ST];
  __shared__ float Lt[IT][ST];
  __shared__ float Dbh[10][ST];
  __shared__ float Vl[ST];
  __shared__ int sbi[IT];
  __shared__ int sbj[JT];
  const int b = blockIdx.z;
  const int i0 = blockIdx.y * IT;
  const int j0 = blockIdx.x * JT;
  const int tid = threadIdx.x;

  for (int f = tid; f < JT * 16; f += 256) {
    int r = f >> 4, h4 = f & 15;
    *(float4*)&Rt[r][h4 * 4] =
        *(const float4*)&right[((size_t)b * NN + j0 + r) * HH + h4 * 4];
  }
  {
    int r = tid >> 4, h4 = tid & 15;
    *(float4*)&Lt[r][h4 * 4] =
        *(const float4*)&left[((size_t)b * NN + i0 + r) * HH + h4 * 4];
  }
  for (int f = tid; f < 160; f += 256) {
    int bk = f >> 4, h4 = f & 15;
    float4 d = *(const float4*)&dist_emb[bk * HH + h4 * 4];
    float4 bh = *(const float4*)&b_h[h4 * 4];
    d.x += bh.x; d.y += bh.y; d.z += bh.z; d.w += bh.w;
    *(float4*)&Dbh[bk][h4 * 4] = d;
  }
  if (tid < 16) *(float4*)&Vl[tid * 4] = *(const float4*)&v_out[tid * 4];
  if (tid >= 64 && tid < 64 + IT) sbi[tid - 64] = span_begin[b * NN + i0 + tid - 64];
  if (tid >= 128 && tid < 128 + JT) sbj[tid - 128] = span_begin[b * NN + j0 + tid - 128];
  __syncthreads();
  {
    const int i = tid >> 4, h4 = tid & 15;
    const float4 l4 = *(const float4*)&Lt[i][h4 * 4];
#pragma unroll
    for (int bk = 0; bk < 10; ++bk) {
      float4 d = *(const float4*)&Dbh[bk][h4 * 4];
      d.x += l4.x; d.y += l4.y; d.z += l4.z; d.w += l4.w;
      *(float4*)&LDb[i * 10 + bk][h4 * 4] = d;
    }
  }
  __syncthreads();

  const int i = tid >> 4, jq = tid & 15;
  const float* LDbF = &LDb[0][0];
  const int my_sbi = sbi[i];
  int rowL[4];
#pragma unroll
  for (int jj = 0; jj < 4; ++jj) {
    const int jl = jq * 4 + jj;
    int d = sbj[jl] - my_sbi;
    d = d < 0 ? -d : d;
    const int bk =
        d <= 4 ? d : (d <= 7 ? 5 : (d <= 15 ? 6 : (d <= 31 ? 7 : (d <= 63 ? 8 : 9))));
    rowL[jj] = (i * 10 + bk) * ST;
  }
  float acc[4] = {0.f, 0.f, 0.f, 0.f};
#pragma unroll
  for (int hq = 0; hq < 16; ++hq) {
    const float4 v4 = *(const float4*)&Vl[hq * 4];
#pragma unroll
    for (int jj = 0; jj < 4; ++jj) {
      const float4 z = *(const float4*)&LDbF[rowL[jj] + hq * 4];
      const float4 r4 = *(const float4*)&Rt[jq * 4 + jj][hq * 4];
      float x0 = fmaxf(z.x + r4.x, 0.f);
      float x1 = fmaxf(z.y + r4.y, 0.f);
      float x2 = fmaxf(z.z + r4.z, 0.f);
      float x3 = fmaxf(z.w + r4.w, 0.f);
      acc[jj] = fmaf(x0, v4.x, acc[jj]);
      acc[jj] = fmaf(x1, v4.y, acc[jj]);
      acc[jj] = fmaf(x2, v4.z, acc[jj]);
      acc[jj] = fmaf(x3, v4.w, acc[jj]);
    }
  }
  const size_t rowoff = ((size_t)b * NN + i0 + i) * NN + j0 + jq * 4;
  const float4 m4 = *(const float4*)&mask[rowoff];
  float4 s4;
  s4.x = acc[0] - (1.0f - m4.x) * 1e23f;
  s4.y = acc[1] - (1.0f - m4.y) * 1e23f;
  s4.z = acc[2] - (1.0f - m4.z) * 1e23f;
  s4.w = acc[3] - (1.0f - m4.w) * 1e23f;
  *(float4*)&scores[rowoff] = s4;
}

// ---------- softmax_bf: row softmax, fp32 scores -> bf16 probs ----------
__global__ __launch_bounds__(256) void softmax_bf(
    const float* __restrict__ scores, ushort* __restrict__ pbf) {
  const int wave = threadIdx.x >> 6, lane = threadIdx.x & 63;
  const int row = blockIdx.x * 4 + wave;
  const float4* p = (const float4*)(scores + (size_t)row * NN);
  float4 v[4];
  float mx = -3.0e38f;
#pragma unroll
  for (int q = 0; q < 4; ++q) {
    v[q] = p[lane + q * 64];
    mx = fmaxf(mx, fmaxf(fmaxf(v[q].x, v[q].y), fmaxf(v[q].z, v[q].w)));
  }
#pragma unroll
  for (int off = 32; off; off >>= 1) mx = fmaxf(mx, __shfl_xor(mx, off));
  float sum = 0.f;
#pragma unroll
  for (int q = 0; q < 4; ++q) {
    v[q].x = __expf(v[q].x - mx); v[q].y = __expf(v[q].y - mx);
    v[q].z = __expf(v[q].z - mx); v[q].w = __expf(v[q].w - mx);
    sum += v[q].x + v[q].y + v[q].z + v[q].w;
  }
#pragma unroll
  for (int off = 32; off; off >>= 1) sum += __shfl_xor(sum, off);
  const float inv = 1.0f / sum;
  ushort4* ob = (ushort4*)(pbf + (size_t)row * NN);
#pragma unroll
  for (int q = 0; q < 4; ++q) {
    ushort4 o = make_ushort4(f2bf(v[q].x * inv), f2bf(v[q].y * inv),
                             f2bf(v[q].z * inv), f2bf(v[q].w * inv));
    ob[lane + q * 64] = o;
  }
}

// -------- ctxt = P @ U via bf16 MFMA. A=probs_bf [b][1024][1024], B=UT [b][512][1024] --------
// 64x64 block tile, 4 waves of 32x32 (2x2 16x16x32 MFMA tiles), BK=64, xor-swizzled LDS.
__global__ __launch_bounds__(256) void gemm_ctxt_mfma(
    const ushort* __restrict__ Pbf, const ushort* __restrict__ UT,
    float* __restrict__ Cf, ushort* __restrict__ Cbf) {
  __shared__ ushort As[64 * 64];
  __shared__ ushort Bs[64 * 64];
  const int b = blockIdx.z;
  const int m0 = blockIdx.y * 64, n0 = blockIdx.x * 64;
  const int tid = threadIdx.x;
  const int lane = tid & 63, wave = tid >> 6;
  const int wm = (wave >> 1) * 32, wn = (wave & 1) * 32;
  const ushort* Ab = Pbf + (size_t)b * NN * NN;
  const ushort* Bb = UT + (size_t)b * DD * NN;
  f32x4 acc[2][2] = {};
  const int fm = lane & 15, quad = lane >> 4;
  for (int k0 = 0; k0 < NN; k0 += 64) {
#pragma unroll
    for (int t = 0; t < 2; ++t) {
      const int idx = tid + t * 256;
      const int r = idx >> 3, c8 = idx & 7;
      const int g = c8 ^ (r & 7);            // xor swizzle on GLOBAL chunk
      GLDS(Ab + (size_t)(m0 + r) * NN + k0 + g * 8, As + idx * 8);
      GLDS(Bb + (size_t)(n0 + r) * NN + k0 + g * 8, Bs + idx * 8);
    }
    __syncthreads();
#pragma unroll
    for (int s = 0; s < 2; ++s) {
      bf16x8 af[2], bfr[2];
#pragma unroll
      for (int tm = 0; tm < 2; ++tm) {
        const int row = wm + tm * 16 + fm;
        const int c8 = (s * 4 + quad) ^ (row & 7);
        af[tm] = *(const bf16x8*)&As[row * 64 + c8 * 8];
      }
#pragma unroll
      for (int tn = 0; tn < 2; ++tn) {
        const int row = wn + tn * 16 + fm;
        const int c8 = (s * 4 + quad) ^ (row & 7);
        bfr[tn] = *(const bf16x8*)&Bs[row * 64 + c8 * 8];
      }
#pragma unroll
      for (int tm = 0; tm < 2; ++tm)
#pragma unroll
        for (int tn = 0; tn < 2; ++tn)
          acc[tm][tn] = __builtin_amdgcn_mfma_f32_16x16x32_bf16(
              af[tm], bfr[tn], acc[tm][tn], 0, 0, 0);
    }
    __syncthreads();
  }
#pragma unroll
  for (int tm = 0; tm < 2; ++tm)
#pragma unroll
    for (int tn = 0; tn < 2; ++tn) {
      const int col = n0 + wn + tn * 16 + fm;
#pragma unroll
      for (int r = 0; r < 4; ++r) {
        const int row = m0 + wm + tm * 16 + quad * 4 + r;
        const float vv = acc[tm][tn][r];
        const size_t off = (size_t)b * NN * DD + (size_t)row * DD + col;
        Cf[off] = vv;
        Cbf[off] = f2bf(vv);
      }
    }
}

// -------- gate GEMM: concat[Ubf|Cbf] @ Wg via bf16 MFMA + sigmoid/blend epilogue --------
__global__ __launch_bounds__(256) void gemm_gate_mfma(
    const ushort* __restrict__ Ubf, const ushort* __restrict__ Cbf,
    const ushort* __restrict__ WgT, const float* __restrict__ bg,
    const float* __restrict__ Uf, const float* __restrict__ Cf,
    float* __restrict__ Uout) {
  __shared__ ushort As[64 * 64];
  __shared__ ushort Bs[64 * 64];
  const int b = blockIdx.z;
  const int m0 = blockIdx.y * 64, n0 = blockIdx.x * 64;
  const int tid = threadIdx.x;
  const int lane = tid & 63, wave = tid >> 6;
  const int wm = (wave >> 1) * 32, wn = (wave & 1) * 32;
  f32x4 acc[2][2] = {};
  const int fm = lane & 15, quad = lane >> 4;
  for (int k0 = 0; k0 < 2 * DD; k0 += 64) {
    const ushort* Abase = (k0 < DD) ? (Ubf + (size_t)b * NN * DD)
                                    : (Cbf + (size_t)b * NN * DD);
    const int kc = k0 & (DD - 1);
#pragma unroll
    for (int t = 0; t < 2; ++t) {
      const int idx = tid + t * 256;
      const int r = idx >> 3, c8 = idx & 7;
      const int g = c8 ^ (r & 7);
      GLDS(Abase + (size_t)(m0 + r) * DD + kc + g * 8, As + idx * 8);
      GLDS(WgT + (size_t)(n0 + r) * (2 * DD) + k0 + g * 8, Bs + idx * 8);
    }
    __syncthreads();
#pragma unroll
    for (int s = 0; s < 2; ++s) {
      bf16x8 af[2], bfr[2];
#pragma unroll
      for (int tm = 0; tm < 2; ++tm) {
        const int row = wm + tm * 16 + fm;
        const int c8 = (s * 4 + quad) ^ (row & 7);
        af[tm] = *(const bf16x8*)&As[row * 64 + c8 * 8];
      }
#pragma unroll
      for (int tn = 0; tn < 2; ++tn) {
        const int row = wn + tn * 16 + fm;
        const int c8 = (s * 4 + quad) ^ (row & 7);
        bfr[tn] = *(const bf16x8*)&Bs[row * 64 + c8 * 8];
      }
#pragma unroll
      for (int tm = 0; tm < 2; ++tm)
#pragma unroll
        for (int tn = 0; tn < 2; ++tn)
          acc[tm][tn] = __builtin_amdgcn_mfma_f32_16x16x32_bf16(
              af[tm], bfr[tn], acc[tm][tn], 0, 0, 0);
    }
    __syncthreads();
  }
#pragma unroll
  for (int tm = 0; tm < 2; ++tm)
#pragma unroll
    for (int tn = 0; tn < 2; ++tn) {
      const int col = n0 + wn + tn * 16 + fm;
      const float bgv = bg[col];
#pragma unroll
      for (int r = 0; r < 4; ++r) {
        const int row = m0 + wm + tm * 16 + quad * 4 + r;
        const size_t off = (size_t)b * NN * DD + (size_t)row * DD + col;
        const float g = 1.f / (1.f + __expf(-(acc[tm][tn][r] + bgv)));
        Uout[off] = g * Uf[off] + (1.f - g) * Cf[off];
      }
    }
}

// --------- output assembly: out = [cand copy | final update copy] ----------
__global__ __launch_bounds__(256) void out_copy(
    const float* __restrict__ cand, const float* __restrict__ upd,
    float* __restrict__ out) {
  const int t = blockIdx.x * 256 + threadIdx.x;
  float4* o4 = (float4*)out;
  if (t < 524288) o4[t] = ((const float4*)cand)[t];
  else o4[t] = ((const float4*)upd)[t - 524288];
}

// --------- scatter: cand_new[b, prune[b,i], :] = upd[b,i,:] for i < span_len[b] ---------
__global__ __launch_bounds__(128) void scatter_k(
    float* __restrict__ out_cand, const float* __restrict__ upd,
    const int* __restrict__ prune, const int* __restrict__ span_len) {
  const int row = blockIdx.x;
  const int b = row >> 10, i = row & 1023;
  if (i >= span_len[b]) return;
  const int dst = prune[row];
  const float4* src = (const float4*)(upd + (size_t)row * DD);
  float4* d = (float4*)(out_cand + ((size_t)b * MM + dst) * DD);
  d[threadIdx.x] = src[threadIdx.x];
}

extern "C" void kernel_launch(void* const* d_in, const int* in_sizes, int n_in,
                              void* d_out, int out_size, void* d_ws, size_t ws_size,
                              hipStream_t stream) {
  const float* update = (const float*)d_in[0];
  const float* mask = (const float*)d_in[1];
  const float* cand = (const float*)d_in[2];
  const int* span_begin = (const int*)d_in[3];
  const int* prune = (const int*)d_in[5];
  const int* span_len = (const int*)d_in[6];
  const float* Wl = (const float*)d_in[7];
  const float* Wr = (const float*)d_in[8];
  const float* b_h = (const float*)d_in[9];
  const float* dist_emb = (const float*)d_in[10];
  const float* v_out = (const float*)d_in[11];
  const float* Wg = (const float*)d_in[13];
  const float* b_gate = (const float*)d_in[14];

  // workspace layout, ~31.5 MB, everything written before read each call
  char* w = (char*)d_ws;
  float* left = (float*)w;      w += (size_t)NB * NN * HH * 4;     // 512 KB
  float* right = (float*)w;     w += (size_t)NB * NN * HH * 4;     // 512 KB
  float* scores = (float*)w;    w += (size_t)NB * NN * NN * 4;     // 8 MB
  ushort* probs_bf = (ushort*)w; w += (size_t)NB * NN * NN * 2;    // 4 MB
  float* ctxt_f = (float*)w;    w += (size_t)NB * NN * DD * 4;     // 4 MB
  ushort* ctxt_bf = (ushort*)w; w += (size_t)NB * NN * DD * 2;     // 2 MB
  float* upd1 = (float*)w;      w += (size_t)NB * NN * DD * 4;     // 4 MB
  float* upd2 = (float*)w;      w += (size_t)NB * NN * DD * 4;     // 4 MB
  ushort* Ubf = (ushort*)w;     w += (size_t)NB * NN * DD * 2;     // 2 MB
  ushort* UT = (ushort*)w;      w += (size_t)NB * NN * DD * 2;     // 2 MB
  ushort* WgT = (ushort*)w;     w += (size_t)2 * DD * DD * 2;      // 1 MB

  float* out = (float*)d_out;

  // Wg [1024][512] -> WgT bf16 [512][1024], once
  conv_t<<<dim3(8, 16, 1), 256, 0, stream>>>(Wg, WgT, WgT, 2 * DD, DD, 0);

  const float* Ucur = update;
  float* nexts[2] = {upd1, upd2};
  for (int it = 0; it < 2; ++it) {
    lr_kernel<<<256, 256, 0, stream>>>(Ucur, Wl, Wr, left, right);
    // U [b][1024][512] -> Ubf row-major + UT [b][512][1024]
    conv_t<<<dim3(8, 16, NB), 256, 0, stream>>>(Ucur, Ubf, UT, NN, DD, 1);
    score_compute<<<dim3(NN / JT, NN / IT, NB), 256, 0, stream>>>(
        left, right, span_begin, mask, dist_emb, b_h, v_out, scores);
    softmax_bf<<<NB * NN / 4, 256, 0, stream>>>(scores, probs_bf);
    gemm_ctxt_mfma<<<dim3(8, 16, NB), 256, 0, stream>>>(probs_bf, UT, ctxt_f, ctxt_bf);
    gemm_gate_mfma<<<dim3(8, 16, NB), 256, 0, stream>>>(Ubf, ctxt_bf, WgT, b_gate,
                                                        Ucur, ctxt_f, nexts[it]);
    Ucur = nexts[it];
  }
  out_copy<<<3072, 256, 0, stream>>>(cand, Ucur, out);
  scatter_k<<<NB * NN, 128, 0, stream>>>(out, Ucur, prune, span_len);
}

// Round 6
// 241.136 us; speedup vs baseline: 2.0436x; 1.0817x over previous
//
#include <hip/hip_runtime.h>
#include <cstdint>

#define NB 2
#define NN 1024
#define MM 2048
#define DD 512
#define HH 64
#define ST 68          // padded LDS stride (floats)

typedef __attribute__((ext_vector_type(8))) short bf16x8;
typedef __attribute__((ext_vector_type(4))) float f32x4;

__device__ inline ushort f2bf(float x) {
  union { float f; uint32_t u; } v; v.f = x;
  uint32_t u = v.u;
  u += 0x7FFF + ((u >> 16) & 1);      // RNE
  return (ushort)(u >> 16);
}

#define GLDS(gp, lp) \
  __builtin_amdgcn_global_load_lds( \
      (const __attribute__((address_space(1))) void*)(gp), \
      (__attribute__((address_space(3))) void*)(lp), 16, 0, 0)

// ---------------- left = U@Wl, right = U@Wr : (2048,512)x(512,64) ----------------
__global__ __launch_bounds__(256) void lr_kernel(
    const float* __restrict__ U, const float* __restrict__ Wl,
    const float* __restrict__ Wr, float* __restrict__ left,
    float* __restrict__ right) {
  __shared__ float u[8][DD];
  const int block = blockIdx.x;
  const int tid = threadIdx.x;
  const float4* Uv = (const float4*)(U + (size_t)block * 8 * DD);
  float4* uv = (float4*)&u[0][0];
#pragma unroll
  for (int t = 0; t < 4; ++t) uv[tid + t * 256] = Uv[tid + t * 256];
  __syncthreads();
  const int h = tid & 63;
  const int isR = (tid >> 6) & 1;
  const int rbase = tid >> 7;
  const float* __restrict__ W = isR ? Wr : Wl;
  float acc[4] = {0.f, 0.f, 0.f, 0.f};
  for (int k0 = 0; k0 < DD; k0 += 4) {
    float w0 = W[(k0 + 0) * HH + h];
    float w1 = W[(k0 + 1) * HH + h];
    float w2 = W[(k0 + 2) * HH + h];
    float w3 = W[(k0 + 3) * HH + h];
#pragma unroll
    for (int r = 0; r < 4; ++r) {
      float4 u4 = *(const float4*)&u[rbase + r * 2][k0];
      acc[r] = fmaf(u4.w, w3, fmaf(u4.z, w2, fmaf(u4.y, w1, fmaf(u4.x, w0, acc[r]))));
    }
  }
  float* out = isR ? right : left;
#pragma unroll
  for (int r = 0; r < 4; ++r)
    out[(size_t)(block * 8 + rbase + r * 2) * HH + h] = acc[r];
}

// ------- conv_t: fp32 [R][C] -> optional bf16 row-major + bf16 transposed [C][R] -------
__global__ __launch_bounds__(256) void conv_t(
    const float* __restrict__ in, ushort* __restrict__ out_row,
    ushort* __restrict__ out_T, int R, int C, int write_row) {
  __shared__ float tile[64][65];
  const int b = blockIdx.z;
  const int r0 = blockIdx.y * 64, c0 = blockIdx.x * 64;
  const int tx = threadIdx.x & 15, ty = threadIdx.x >> 4;
  const float* inb = in + (size_t)b * R * C;
#pragma unroll
  for (int p = 0; p < 4; ++p) {
    const int r = ty + p * 16;
    const float4 v = *(const float4*)&inb[(size_t)(r0 + r) * C + c0 + tx * 4];
    tile[r][tx * 4 + 0] = v.x; tile[r][tx * 4 + 1] = v.y;
    tile[r][tx * 4 + 2] = v.z; tile[r][tx * 4 + 3] = v.w;
    if (write_row) {
      ushort4 o = make_ushort4(f2bf(v.x), f2bf(v.y), f2bf(v.z), f2bf(v.w));
      *(ushort4*)&out_row[(size_t)b * R * C + (size_t)(r0 + r) * C + c0 + tx * 4] = o;
    }
  }
  __syncthreads();
  ushort* oT = out_T + (size_t)b * R * C;
#pragma unroll
  for (int p = 0; p < 4; ++p) {
    const int rr = ty + p * 16;
    ushort4 o;
    o.x = f2bf(tile[tx * 4 + 0][rr]);
    o.y = f2bf(tile[tx * 4 + 1][rr]);
    o.z = f2bf(tile[tx * 4 + 2][rr]);
    o.w = f2bf(tile[tx * 4 + 3][rr]);
    *(ushort4*)&oT[(size_t)(c0 + rr) * R + r0 + tx * 4] = o;
  }
}

// ---- fused score + softmax -> bf16 probs. 4 rows/block (1 row per wave). ----
// Scores staged in LDS (not a 16-deep register array) and the j-chunk loop is
// NOT unrolled: keeps codegen small (R4/R5's fully-unrolled version was the
// prime suspect for the build-level failure).
__global__ __launch_bounds__(256) void score_softmax(
    const float* __restrict__ left, const float* __restrict__ right,
    const int* __restrict__ span_begin, const float* __restrict__ mask,
    const float* __restrict__ dist_emb, const float* __restrict__ b_h,
    const float* __restrict__ v_out, ushort* __restrict__ probs_bf) {
  __shared__ float Rt[64][ST];         // 17.4 KB  current j-chunk of right
  __shared__ float LDb[4][10][ST];     // 10.9 KB  left_i + dist[bk] + b_h
  __shared__ float Dbh[10][ST];        //  2.7 KB
  __shared__ float Lt[4][ST];          //  1.1 KB
  __shared__ float Vl[ST];             //  0.3 KB
  __shared__ float Sc[4][NN];          // 16.0 KB  raw scores per row
  __shared__ int sbj[NN];              //  4.0 KB          (total ~52.8 KB)
  const int b = blockIdx.y;
  const int r0 = blockIdx.x * 4;
  const int tid = threadIdx.x;
  const int wave = tid >> 6, lane = tid & 63;
  const int row = r0 + wave;

  for (int f = tid; f < 160; f += 256) {
    int bk = f >> 4, h4 = f & 15;
    float4 d = *(const float4*)&dist_emb[bk * HH + h4 * 4];
    float4 bh = *(const float4*)&b_h[h4 * 4];
    d.x += bh.x; d.y += bh.y; d.z += bh.z; d.w += bh.w;
    *(float4*)&Dbh[bk][h4 * 4] = d;
  }
  if (tid < 64) {
    int r = tid >> 4, h4 = tid & 15;
    *(float4*)&Lt[r][h4 * 4] =
        *(const float4*)&left[((size_t)b * NN + r0 + r) * HH + h4 * 4];
  }
  if (tid >= 64 && tid < 80)
    *(float4*)&Vl[(tid - 64) * 4] = *(const float4*)&v_out[(tid - 64) * 4];
  for (int t = tid; t < NN; t += 256) sbj[t] = span_begin[b * NN + t];
  __syncthreads();
  for (int f = tid; f < 640; f += 256) {
    int i = f / 160, rem = f - i * 160;
    int bk = rem >> 4, h4 = rem & 15;
    float4 l = *(const float4*)&Lt[i][h4 * 4];
    float4 d = *(const float4*)&Dbh[bk][h4 * 4];
    d.x += l.x; d.y += l.y; d.z += l.z; d.w += l.w;
    *(float4*)&LDb[i][bk][h4 * 4] = d;
  }
  float4 vr[16];
#pragma unroll
  for (int hq = 0; hq < 16; ++hq) vr[hq] = *(const float4*)&Vl[hq * 4];
  const int my_sbi = span_begin[(size_t)b * NN + row];
  const float* maskrow = mask + ((size_t)b * NN + row) * NN;

#pragma unroll 1
  for (int c = 0; c < 16; ++c) {
    __syncthreads();                   // Rt reuse boundary (covers LDb fill at c=0)
#pragma unroll
    for (int t = 0; t < 4; ++t) {
      const int f = tid + t * 256;
      const int r = f >> 4, h4 = f & 15;
      *(float4*)&Rt[r][h4 * 4] =
          *(const float4*)&right[((size_t)b * NN + c * 64 + r) * HH + h4 * 4];
    }
    __syncthreads();
    int d = sbj[c * 64 + lane] - my_sbi;
    d = d < 0 ? -d : d;
    const int bk =
        d <= 4 ? d : (d <= 7 ? 5 : (d <= 15 ? 6 : (d <= 31 ? 7 : (d <= 63 ? 8 : 9))));
    const float* zp = &LDb[wave][bk][0];
    const float* rp = &Rt[lane][0];
    float acc = 0.f;
#pragma unroll
    for (int hq = 0; hq < 16; ++hq) {
      const float4 z = *(const float4*)&zp[hq * 4];
      const float4 r4 = *(const float4*)&rp[hq * 4];
      float x0 = fmaxf(z.x + r4.x, 0.f);
      float x1 = fmaxf(z.y + r4.y, 0.f);
      float x2 = fmaxf(z.z + r4.z, 0.f);
      float x3 = fmaxf(z.w + r4.w, 0.f);
      acc = fmaf(x0, vr[hq].x, acc);
      acc = fmaf(x1, vr[hq].y, acc);
      acc = fmaf(x2, vr[hq].z, acc);
      acc = fmaf(x3, vr[hq].w, acc);
    }
    const float mval = maskrow[c * 64 + lane];
    Sc[wave][c * 64 + lane] = acc - (1.0f - mval) * 1e23f;
  }
  // wave softmax over this wave's private row (Sc row is wave-private)
  float mx = -3.0e38f;
#pragma unroll
  for (int c = 0; c < 16; ++c) mx = fmaxf(mx, Sc[wave][c * 64 + lane]);
#pragma unroll
  for (int off = 32; off; off >>= 1) mx = fmaxf(mx, __shfl_xor(mx, off));
  float sum = 0.f;
#pragma unroll
  for (int c = 0; c < 16; ++c) {
    const float e = __expf(Sc[wave][c * 64 + lane] - mx);
    Sc[wave][c * 64 + lane] = e;
    sum += e;
  }
#pragma unroll
  for (int off = 32; off; off >>= 1) sum += __shfl_xor(sum, off);
  const float inv = 1.0f / sum;
  ushort* prow = probs_bf + ((size_t)b * NN + row) * NN;
#pragma unroll
  for (int c = 0; c < 16; ++c)
    prow[c * 64 + lane] = f2bf(Sc[wave][c * 64 + lane] * inv);
}

// -------- ctxt = P @ U via bf16 MFMA. A=probs_bf [b][1024][1024], B=UT [b][512][1024] --------
__global__ __launch_bounds__(256) void gemm_ctxt_mfma(
    const ushort* __restrict__ Pbf, const ushort* __restrict__ UT,
    float* __restrict__ Cf, ushort* __restrict__ Cbf) {
  __shared__ ushort As[64 * 64];
  __shared__ ushort Bs[64 * 64];
  const int b = blockIdx.z;
  const int m0 = blockIdx.y * 64, n0 = blockIdx.x * 64;
  const int tid = threadIdx.x;
  const int lane = tid & 63, wave = tid >> 6;
  const int wm = (wave >> 1) * 32, wn = (wave & 1) * 32;
  const ushort* Ab = Pbf + (size_t)b * NN * NN;
  const ushort* Bb = UT + (size_t)b * DD * NN;
  f32x4 acc[2][2] = {};
  const int fm = lane & 15, quad = lane >> 4;
  for (int k0 = 0; k0 < NN; k0 += 64) {
#pragma unroll
    for (int t = 0; t < 2; ++t) {
      const int idx = tid + t * 256;
      const int r = idx >> 3, c8 = idx & 7;
      const int g = c8 ^ (r & 7);
      GLDS(Ab + (size_t)(m0 + r) * NN + k0 + g * 8, As + idx * 8);
      GLDS(Bb + (size_t)(n0 + r) * NN + k0 + g * 8, Bs + idx * 8);
    }
    __syncthreads();
#pragma unroll
    for (int s = 0; s < 2; ++s) {
      bf16x8 af[2], bfr[2];
#pragma unroll
      for (int tm = 0; tm < 2; ++tm) {
        const int row = wm + tm * 16 + fm;
        const int c8 = (s * 4 + quad) ^ (row & 7);
        af[tm] = *(const bf16x8*)&As[row * 64 + c8 * 8];
      }
#pragma unroll
      for (int tn = 0; tn < 2; ++tn) {
        const int row = wn + tn * 16 + fm;
        const int c8 = (s * 4 + quad) ^ (row & 7);
        bfr[tn] = *(const bf16x8*)&Bs[row * 64 + c8 * 8];
      }
#pragma unroll
      for (int tm = 0; tm < 2; ++tm)
#pragma unroll
        for (int tn = 0; tn < 2; ++tn)
          acc[tm][tn] = __builtin_amdgcn_mfma_f32_16x16x32_bf16(
              af[tm], bfr[tn], acc[tm][tn], 0, 0, 0);
    }
    __syncthreads();
  }
#pragma unroll
  for (int tm = 0; tm < 2; ++tm)
#pragma unroll
    for (int tn = 0; tn < 2; ++tn) {
      const int col = n0 + wn + tn * 16 + fm;
#pragma unroll
      for (int r = 0; r < 4; ++r) {
        const int row = m0 + wm + tm * 16 + quad * 4 + r;
        const float vv = acc[tm][tn][r];
        const size_t off = (size_t)b * NN * DD + (size_t)row * DD + col;
        Cf[off] = vv;
        Cbf[off] = f2bf(vv);
      }
    }
}

// -------- gate GEMM + sigmoid/blend epilogue; emits Uout fp32 + bf16 row (to a
// SEPARATE buffer — in-place would race with this kernel's own A-operand reads)
// + bf16 transposed --------
__global__ __launch_bounds__(256) void gemm_gate_mfma(
    const ushort* __restrict__ Ubf, const ushort* __restrict__ Cbf,
    const ushort* __restrict__ WgT, const float* __restrict__ bg,
    const float* __restrict__ Uf, const float* __restrict__ Cf,
    float* __restrict__ Uout, ushort* __restrict__ UbfOut,
    ushort* __restrict__ UTOut) {
  __shared__ ushort As[64 * 64];
  __shared__ ushort Bs[64 * 64];
  __shared__ ushort Tt[64][66];
  const int b = blockIdx.z;
  const int m0 = blockIdx.y * 64, n0 = blockIdx.x * 64;
  const int tid = threadIdx.x;
  const int lane = tid & 63, wave = tid >> 6;
  const int wm = (wave >> 1) * 32, wn = (wave & 1) * 32;
  f32x4 acc[2][2] = {};
  const int fm = lane & 15, quad = lane >> 4;
  for (int k0 = 0; k0 < 2 * DD; k0 += 64) {
    const ushort* Abase = (k0 < DD) ? (Ubf + (size_t)b * NN * DD)
                                    : (Cbf + (size_t)b * NN * DD);
    const int kc = k0 & (DD - 1);
#pragma unroll
    for (int t = 0; t < 2; ++t) {
      const int idx = tid + t * 256;
      const int r = idx >> 3, c8 = idx & 7;
      const int g = c8 ^ (r & 7);
      GLDS(Abase + (size_t)(m0 + r) * DD + kc + g * 8, As + idx * 8);
      GLDS(WgT + (size_t)(n0 + r) * (2 * DD) + k0 + g * 8, Bs + idx * 8);
    }
    __syncthreads();
#pragma unroll
    for (int s = 0; s < 2; ++s) {
      bf16x8 af[2], bfr[2];
#pragma unroll
      for (int tm = 0; tm < 2; ++tm) {
        const int row = wm + tm * 16 + fm;
        const int c8 = (s * 4 + quad) ^ (row & 7);
        af[tm] = *(const bf16x8*)&As[row * 64 + c8 * 8];
      }
#pragma unroll
      for (int tn = 0; tn < 2; ++tn) {
        const int row = wn + tn * 16 + fm;
        const int c8 = (s * 4 + quad) ^ (row & 7);
        bfr[tn] = *(const bf16x8*)&Bs[row * 64 + c8 * 8];
      }
#pragma unroll
      for (int tm = 0; tm < 2; ++tm)
#pragma unroll
        for (int tn = 0; tn < 2; ++tn)
          acc[tm][tn] = __builtin_amdgcn_mfma_f32_16x16x32_bf16(
              af[tm], bfr[tn], acc[tm][tn], 0, 0, 0);
    }
    __syncthreads();
  }
#pragma unroll
  for (int tm = 0; tm < 2; ++tm)
#pragma unroll
    for (int tn = 0; tn < 2; ++tn) {
      const int cl = wn + tn * 16 + fm;
      const int col = n0 + cl;
      const float bgv = bg[col];
#pragma unroll
      for (int r = 0; r < 4; ++r) {
        const int rl = wm + tm * 16 + quad * 4 + r;
        const int row = m0 + rl;
        const size_t off = (size_t)b * NN * DD + (size_t)row * DD + col;
        const float g = 1.f / (1.f + __expf(-(acc[tm][tn][r] + bgv)));
        const float o = g * Uf[off] + (1.f - g) * Cf[off];
        Uout[off] = o;
        const ushort ob = f2bf(o);
        UbfOut[off] = ob;
        Tt[rl][cl] = ob;
      }
    }
  __syncthreads();
  // transposed bf16 write: UT[b][d][n]
#pragma unroll
  for (int p = 0; p < 4; ++p) {
    const int cl = (tid >> 4) + p * 16;
    const int rl = (tid & 15) * 4;
    ushort4 o;
    o.x = Tt[rl + 0][cl]; o.y = Tt[rl + 1][cl];
    o.z = Tt[rl + 2][cl]; o.w = Tt[rl + 3][cl];
    *(ushort4*)&UTOut[((size_t)b * DD + n0 + cl) * NN + m0 + rl] = o;
  }
}

// --------- output assembly: out = [cand copy | final update copy] ----------
__global__ __launch_bounds__(256) void out_copy(
    const float* __restrict__ cand, const float* __restrict__ upd,
    float* __restrict__ out) {
  const int t = blockIdx.x * 256 + threadIdx.x;
  float4* o4 = (float4*)out;
  if (t < 524288) o4[t] = ((const float4*)cand)[t];
  else o4[t] = ((const float4*)upd)[t - 524288];
}

// --------- scatter: cand_new[b, prune[b,i], :] = upd[b,i,:] for i < span_len[b] ---------
__global__ __launch_bounds__(128) void scatter_k(
    float* __restrict__ out_cand, const float* __restrict__ upd,
    const int* __restrict__ prune, const int* __restrict__ span_len) {
  const int row = blockIdx.x;
  const int b = row >> 10, i = row & 1023;
  if (i >= span_len[b]) return;
  const int dst = prune[row];
  const float4* src = (const float4*)(upd + (size_t)row * DD);
  float4* d = (float4*)(out_cand + ((size_t)b * MM + dst) * DD);
  d[threadIdx.x] = src[threadIdx.x];
}

extern "C" void kernel_launch(void* const* d_in, const int* in_sizes, int n_in,
                              void* d_out, int out_size, void* d_ws, size_t ws_size,
                              hipStream_t stream) {
  const float* update = (const float*)d_in[0];
  const float* mask = (const float*)d_in[1];
  const float* cand = (const float*)d_in[2];
  const int* span_begin = (const int*)d_in[3];
  const int* prune = (const int*)d_in[5];
  const int* span_len = (const int*)d_in[6];
  const float* Wl = (const float*)d_in[7];
  const float* Wr = (const float*)d_in[8];
  const float* b_h = (const float*)d_in[9];
  const float* dist_emb = (const float*)d_in[10];
  const float* v_out = (const float*)d_in[11];
  const float* Wg = (const float*)d_in[13];
  const float* b_gate = (const float*)d_in[14];

  char* w = (char*)d_ws;
  float* left = (float*)w;       w += (size_t)NB * NN * HH * 4;    // 512 KB
  float* right = (float*)w;      w += (size_t)NB * NN * HH * 4;    // 512 KB
  ushort* probs_bf = (ushort*)w; w += (size_t)NB * NN * NN * 2;    // 4 MB
  float* ctxt_f = (float*)w;     w += (size_t)NB * NN * DD * 4;    // 4 MB
  ushort* ctxt_bf = (ushort*)w;  w += (size_t)NB * NN * DD * 2;    // 2 MB
  float* upd1 = (float*)w;       w += (size_t)NB * NN * DD * 4;    // 4 MB
  float* upd2 = (float*)w;       w += (size_t)NB * NN * DD * 4;    // 4 MB
  ushort* Ubf0 = (ushort*)w;     w += (size_t)NB * NN * DD * 2;    // 2 MB
  ushort* Ubf1 = (ushort*)w;     w += (size_t)NB * NN * DD * 2;    // 2 MB (race fix)
  ushort* UT = (ushort*)w;       w += (size_t)NB * NN * DD * 2;    // 2 MB
  ushort* WgT = (ushort*)w;      w += (size_t)2 * DD * DD * 2;     // 1 MB

  float* out = (float*)d_out;

  // Wg [1024][512] -> WgT bf16 [512][1024]; update -> Ubf0 + UT (once)
  conv_t<<<dim3(8, 16, 1), 256, 0, stream>>>(Wg, WgT, WgT, 2 * DD, DD, 0);
  conv_t<<<dim3(8, 16, NB), 256, 0, stream>>>(update, Ubf0, UT, NN, DD, 1);

  const float* Ucur = update;
  float* nexts[2] = {upd1, upd2};
  ushort* ubf_in[2] = {Ubf0, Ubf1};
  ushort* ubf_out[2] = {Ubf1, Ubf0};
  for (int it = 0; it < 2; ++it) {
    lr_kernel<<<256, 256, 0, stream>>>(Ucur, Wl, Wr, left, right);
    score_softmax<<<dim3(NN / 4, NB), 256, 0, stream>>>(
        left, right, span_begin, mask, dist_emb, b_h, v_out, probs_bf);
    gemm_ctxt_mfma<<<dim3(8, 16, NB), 256, 0, stream>>>(probs_bf, UT, ctxt_f, ctxt_bf);
    // epilogue writes next iteration's Ubf (separate buffer!) and UT
    gemm_gate_mfma<<<dim3(8, 16, NB), 256, 0, stream>>>(
        ubf_in[it], ctxt_bf, WgT, b_gate, Ucur, ctxt_f, nexts[it], ubf_out[it], UT);
    Ucur = nexts[it];
  }
  out_copy<<<3072, 256, 0, stream>>>(cand, Ucur, out);
  scatter_k<<<NB * NN, 128, 0, stream>>>(out, Ucur, prune, span_len);
}

// Round 7
// 240.100 us; speedup vs baseline: 2.0524x; 1.0043x over previous
//
#include <hip/hip_runtime.h>
#include <cstdint>

#define NB 2
#define NN 1024
#define MM 2048
#define DD 512
#define HH 64
#define ST 68          // padded LDS stride (floats)
#define STB 72         // padded LDS stride (ushorts), 144 B rows (16B-aligned)

typedef __attribute__((ext_vector_type(8))) short bf16x8;
typedef __attribute__((ext_vector_type(4))) float f32x4;

__device__ inline ushort f2bf(float x) {
  union { float f; uint32_t u; } v; v.f = x;
  uint32_t u = v.u;
  u += 0x7FFF + ((u >> 16) & 1);      // RNE
  return (ushort)(u >> 16);
}
__device__ inline float bflo(uint32_t d) { return __uint_as_float(d << 16); }
__device__ inline float bfhi(uint32_t d) { return __uint_as_float(d & 0xFFFF0000u); }

#define GLDS(gp, lp) \
  __builtin_amdgcn_global_load_lds( \
      (const __attribute__((address_space(1))) void*)(gp), \
      (__attribute__((address_space(3))) void*)(lp), 16, 0, 0)

// ------- left(f32) = U@Wl, right(bf16) = U@Wr : (2048,512)x(512,64) -------
__global__ __launch_bounds__(256) void lr_kernel(
    const float* __restrict__ U, const float* __restrict__ Wl,
    const float* __restrict__ Wr, float* __restrict__ left,
    ushort* __restrict__ right_bf) {
  __shared__ float u[8][DD];
  const int block = blockIdx.x;
  const int tid = threadIdx.x;
  const float4* Uv = (const float4*)(U + (size_t)block * 8 * DD);
  float4* uv = (float4*)&u[0][0];
#pragma unroll
  for (int t = 0; t < 4; ++t) uv[tid + t * 256] = Uv[tid + t * 256];
  __syncthreads();
  const int h = tid & 63;
  const int isR = (tid >> 6) & 1;
  const int rbase = tid >> 7;
  const float* __restrict__ W = isR ? Wr : Wl;
  float acc[4] = {0.f, 0.f, 0.f, 0.f};
  for (int k0 = 0; k0 < DD; k0 += 4) {
    float w0 = W[(k0 + 0) * HH + h];
    float w1 = W[(k0 + 1) * HH + h];
    float w2 = W[(k0 + 2) * HH + h];
    float w3 = W[(k0 + 3) * HH + h];
#pragma unroll
    for (int r = 0; r < 4; ++r) {
      float4 u4 = *(const float4*)&u[rbase + r * 2][k0];
      acc[r] = fmaf(u4.w, w3, fmaf(u4.z, w2, fmaf(u4.y, w1, fmaf(u4.x, w0, acc[r]))));
    }
  }
  if (isR) {
#pragma unroll
    for (int r = 0; r < 4; ++r)
      right_bf[(size_t)(block * 8 + rbase + r * 2) * HH + h] = f2bf(acc[r]);
  } else {
#pragma unroll
    for (int r = 0; r < 4; ++r)
      left[(size_t)(block * 8 + rbase + r * 2) * HH + h] = acc[r];
  }
}

// ------- conv_t: fp32 [R][C] -> optional bf16 row-major + bf16 transposed [C][R] -------
__global__ __launch_bounds__(256) void conv_t(
    const float* __restrict__ in, ushort* __restrict__ out_row,
    ushort* __restrict__ out_T, int R, int C, int write_row) {
  __shared__ float tile[64][65];
  const int b = blockIdx.z;
  const int r0 = blockIdx.y * 64, c0 = blockIdx.x * 64;
  const int tx = threadIdx.x & 15, ty = threadIdx.x >> 4;
  const float* inb = in + (size_t)b * R * C;
#pragma unroll
  for (int p = 0; p < 4; ++p) {
    const int r = ty + p * 16;
    const float4 v = *(const float4*)&inb[(size_t)(r0 + r) * C + c0 + tx * 4];
    tile[r][tx * 4 + 0] = v.x; tile[r][tx * 4 + 1] = v.y;
    tile[r][tx * 4 + 2] = v.z; tile[r][tx * 4 + 3] = v.w;
    if (write_row) {
      ushort4 o = make_ushort4(f2bf(v.x), f2bf(v.y), f2bf(v.z), f2bf(v.w));
      *(ushort4*)&out_row[(size_t)b * R * C + (size_t)(r0 + r) * C + c0 + tx * 4] = o;
    }
  }
  __syncthreads();
  ushort* oT = out_T + (size_t)b * R * C;
#pragma unroll
  for (int p = 0; p < 4; ++p) {
    const int rr = ty + p * 16;
    ushort4 o;
    o.x = f2bf(tile[tx * 4 + 0][rr]);
    o.y = f2bf(tile[tx * 4 + 1][rr]);
    o.z = f2bf(tile[tx * 4 + 2][rr]);
    o.w = f2bf(tile[tx * 4 + 3][rr]);
    *(ushort4*)&oT[(size_t)(c0 + rr) * R + r0 + tx * 4] = o;
  }
}

// ---- fused score + softmax -> bf16 probs. 4 rows/block (1 row per wave). ----
// bf16 LDS operands halve the dominant ds_read_b128 traffic vs the fp32
// version (16 b128/score instead of 32); accumulation stays fp32.
__global__ __launch_bounds__(256) void score_softmax(
    const float* __restrict__ left, const ushort* __restrict__ right_bf,
    const int* __restrict__ span_begin, const float* __restrict__ mask,
    const float* __restrict__ dist_emb, const float* __restrict__ b_h,
    const float* __restrict__ v_out, ushort* __restrict__ probs_bf) {
  __shared__ ushort Rt[64][STB];       //  9.2 KB  current j-chunk of right (bf16)
  __shared__ ushort LDb[4][10][STB];   //  5.8 KB  bf16(left_i + dist[bk] + b_h)
  __shared__ float Dbh[10][ST];        //  2.7 KB
  __shared__ float Lt[4][ST];          //  1.1 KB
  __shared__ float Sc[4][NN];          // 16.0 KB  raw scores per row
  __shared__ int sbj[NN];              //  4.0 KB          (total ~38.8 KB)
  const int b = blockIdx.y;
  const int r0 = blockIdx.x * 4;
  const int tid = threadIdx.x;
  const int wave = tid >> 6, lane = tid & 63;
  const int row = r0 + wave;

  for (int f = tid; f < 160; f += 256) {
    int bk = f >> 4, h4 = f & 15;
    float4 d = *(const float4*)&dist_emb[bk * HH + h4 * 4];
    float4 bh = *(const float4*)&b_h[h4 * 4];
    d.x += bh.x; d.y += bh.y; d.z += bh.z; d.w += bh.w;
    *(float4*)&Dbh[bk][h4 * 4] = d;
  }
  if (tid < 64) {
    int r = tid >> 4, h4 = tid & 15;
    *(float4*)&Lt[r][h4 * 4] =
        *(const float4*)&left[((size_t)b * NN + r0 + r) * HH + h4 * 4];
  }
  for (int t = tid; t < NN; t += 256) sbj[t] = span_begin[b * NN + t];
  __syncthreads();
  // LDb[i][bk][h] = bf16(Lt[i][h] + Dbh[bk][h]); 2560 elems
  for (int f = tid; f < 2560; f += 256) {
    int i = f >> 9;               // f / 640... careful: 4*10*64 = 2560; i = f/640
    i = f / 640;
    int rem = f - i * 640;
    int bk = rem >> 6, h = rem & 63;
    LDb[i][bk][h] = f2bf(Lt[i][h] + Dbh[bk][h]);
  }
  float4 vr[16];
#pragma unroll
  for (int hq = 0; hq < 16; ++hq) vr[hq] = *(const float4*)&v_out[hq * 4];
  const int my_sbi = span_begin[(size_t)b * NN + row];
  const float* maskrow = mask + ((size_t)b * NN + row) * NN;

#pragma unroll 1
  for (int c = 0; c < 16; ++c) {
    __syncthreads();                   // Rt reuse boundary (covers LDb fill at c=0)
    // stage 64 rows x 64 bf16 = 8 KB, 512 x 16B
#pragma unroll
    for (int t = 0; t < 2; ++t) {
      const int f = tid + t * 256;
      const int r = f >> 3, u8 = f & 7;
      *(bf16x8*)&Rt[r][u8 * 8] =
          *(const bf16x8*)&right_bf[((size_t)b * NN + c * 64 + r) * HH + u8 * 8];
    }
    __syncthreads();
    int d = sbj[c * 64 + lane] - my_sbi;
    d = d < 0 ? -d : d;
    const int bk =
        d <= 4 ? d : (d <= 7 ? 5 : (d <= 15 ? 6 : (d <= 31 ? 7 : (d <= 63 ? 8 : 9))));
    const ushort* zp = &LDb[wave][bk][0];
    const ushort* rp = &Rt[lane][0];
    float acc = 0.f;
#pragma unroll
    for (int oct = 0; oct < 8; ++oct) {
      const uint4 zd = *(const uint4*)&zp[oct * 8];
      const uint4 rd = *(const uint4*)&rp[oct * 8];
      const float4 v0 = vr[2 * oct], v1 = vr[2 * oct + 1];
      acc = fmaf(fmaxf(bflo(zd.x) + bflo(rd.x), 0.f), v0.x, acc);
      acc = fmaf(fmaxf(bfhi(zd.x) + bfhi(rd.x), 0.f), v0.y, acc);
      acc = fmaf(fmaxf(bflo(zd.y) + bflo(rd.y), 0.f), v0.z, acc);
      acc = fmaf(fmaxf(bfhi(zd.y) + bfhi(rd.y), 0.f), v0.w, acc);
      acc = fmaf(fmaxf(bflo(zd.z) + bflo(rd.z), 0.f), v1.x, acc);
      acc = fmaf(fmaxf(bfhi(zd.z) + bfhi(rd.z), 0.f), v1.y, acc);
      acc = fmaf(fmaxf(bflo(zd.w) + bflo(rd.w), 0.f), v1.z, acc);
      acc = fmaf(fmaxf(bfhi(zd.w) + bfhi(rd.w), 0.f), v1.w, acc);
    }
    const float mval = maskrow[c * 64 + lane];
    Sc[wave][c * 64 + lane] = acc - (1.0f - mval) * 1e23f;
  }
  // wave softmax over this wave's private row
  float mx = -3.0e38f;
#pragma unroll
  for (int c = 0; c < 16; ++c) mx = fmaxf(mx, Sc[wave][c * 64 + lane]);
#pragma unroll
  for (int off = 32; off; off >>= 1) mx = fmaxf(mx, __shfl_xor(mx, off));
  float sum = 0.f;
#pragma unroll
  for (int c = 0; c < 16; ++c) {
    const float e = __expf(Sc[wave][c * 64 + lane] - mx);
    Sc[wave][c * 64 + lane] = e;
    sum += e;
  }
#pragma unroll
  for (int off = 32; off; off >>= 1) sum += __shfl_xor(sum, off);
  const float inv = 1.0f / sum;
  ushort* prow = probs_bf + ((size_t)b * NN + row) * NN;
#pragma unroll
  for (int c = 0; c < 16; ++c)
    prow[c * 64 + lane] = f2bf(Sc[wave][c * 64 + lane] * inv);
}

// -------- ctxt(bf16) = P @ U via bf16 MFMA. A=probs_bf, B=UT [b][512][1024] --------
__global__ __launch_bounds__(256) void gemm_ctxt_mfma(
    const ushort* __restrict__ Pbf, const ushort* __restrict__ UT,
    ushort* __restrict__ Cbf) {
  __shared__ ushort As[64 * 64];
  __shared__ ushort Bs[64 * 64];
  const int b = blockIdx.z;
  const int m0 = blockIdx.y * 64, n0 = blockIdx.x * 64;
  const int tid = threadIdx.x;
  const int lane = tid & 63, wave = tid >> 6;
  const int wm = (wave >> 1) * 32, wn = (wave & 1) * 32;
  const ushort* Ab = Pbf + (size_t)b * NN * NN;
  const ushort* Bb = UT + (size_t)b * DD * NN;
  f32x4 acc[2][2] = {};
  const int fm = lane & 15, quad = lane >> 4;
  for (int k0 = 0; k0 < NN; k0 += 64) {
#pragma unroll
    for (int t = 0; t < 2; ++t) {
      const int idx = tid + t * 256;
      const int r = idx >> 3, c8 = idx & 7;
      const int g = c8 ^ (r & 7);
      GLDS(Ab + (size_t)(m0 + r) * NN + k0 + g * 8, As + idx * 8);
      GLDS(Bb + (size_t)(n0 + r) * NN + k0 + g * 8, Bs + idx * 8);
    }
    __syncthreads();
#pragma unroll
    for (int s = 0; s < 2; ++s) {
      bf16x8 af[2], bfr[2];
#pragma unroll
      for (int tm = 0; tm < 2; ++tm) {
        const int row = wm + tm * 16 + fm;
        const int c8 = (s * 4 + quad) ^ (row & 7);
        af[tm] = *(const bf16x8*)&As[row * 64 + c8 * 8];
      }
#pragma unroll
      for (int tn = 0; tn < 2; ++tn) {
        const int row = wn + tn * 16 + fm;
        const int c8 = (s * 4 + quad) ^ (row & 7);
        bfr[tn] = *(const bf16x8*)&Bs[row * 64 + c8 * 8];
      }
#pragma unroll
      for (int tm = 0; tm < 2; ++tm)
#pragma unroll
        for (int tn = 0; tn < 2; ++tn)
          acc[tm][tn] = __builtin_amdgcn_mfma_f32_16x16x32_bf16(
              af[tm], bfr[tn], acc[tm][tn], 0, 0, 0);
    }
    __syncthreads();
  }
#pragma unroll
  for (int tm = 0; tm < 2; ++tm)
#pragma unroll
    for (int tn = 0; tn < 2; ++tn) {
      const int col = n0 + wn + tn * 16 + fm;
#pragma unroll
      for (int r = 0; r < 4; ++r) {
        const int row = m0 + wm + tm * 16 + quad * 4 + r;
        Cbf[(size_t)b * NN * DD + (size_t)row * DD + col] = f2bf(acc[tm][tn][r]);
      }
    }
}

// -------- gate GEMM + sigmoid/blend epilogue; blend uses Uf(fp32) + Cbf(bf16).
// Emits Uout fp32, bf16 row (separate buffer from A-operand!) and bf16 T. --------
__global__ __launch_bounds__(256) void gemm_gate_mfma(
    const ushort* __restrict__ Ubf, const ushort* __restrict__ Cbf,
    const ushort* __restrict__ WgT, const float* __restrict__ bg,
    const float* __restrict__ Uf, float* __restrict__ Uout,
    ushort* __restrict__ UbfOut, ushort* __restrict__ UTOut) {
  __shared__ ushort As[64 * 64];
  __shared__ ushort Bs[64 * 64];
  __shared__ ushort Tt[64][66];
  const int b = blockIdx.z;
  const int m0 = blockIdx.y * 64, n0 = blockIdx.x * 64;
  const int tid = threadIdx.x;
  const int lane = tid & 63, wave = tid >> 6;
  const int wm = (wave >> 1) * 32, wn = (wave & 1) * 32;
  f32x4 acc[2][2] = {};
  const int fm = lane & 15, quad = lane >> 4;
  for (int k0 = 0; k0 < 2 * DD; k0 += 64) {
    const ushort* Abase = (k0 < DD) ? (Ubf + (size_t)b * NN * DD)
                                    : (Cbf + (size_t)b * NN * DD);
    const int kc = k0 & (DD - 1);
#pragma unroll
    for (int t = 0; t < 2; ++t) {
      const int idx = tid + t * 256;
      const int r = idx >> 3, c8 = idx & 7;
      const int g = c8 ^ (r & 7);
      GLDS(Abase + (size_t)(m0 + r) * DD + kc + g * 8, As + idx * 8);
      GLDS(WgT + (size_t)(n0 + r) * (2 * DD) + k0 + g * 8, Bs + idx * 8);
    }
    __syncthreads();
#pragma unroll
    for (int s = 0; s < 2; ++s) {
      bf16x8 af[2], bfr[2];
#pragma unroll
      for (int tm = 0; tm < 2; ++tm) {
        const int row = wm + tm * 16 + fm;
        const int c8 = (s * 4 + quad) ^ (row & 7);
        af[tm] = *(const bf16x8*)&As[row * 64 + c8 * 8];
      }
#pragma unroll
      for (int tn = 0; tn < 2; ++tn) {
        const int row = wn + tn * 16 + fm;
        const int c8 = (s * 4 + quad) ^ (row & 7);
        bfr[tn] = *(const bf16x8*)&Bs[row * 64 + c8 * 8];
      }
#pragma unroll
      for (int tm = 0; tm < 2; ++tm)
#pragma unroll
        for (int tn = 0; tn < 2; ++tn)
          acc[tm][tn] = __builtin_amdgcn_mfma_f32_16x16x32_bf16(
              af[tm], bfr[tn], acc[tm][tn], 0, 0, 0);
    }
    __syncthreads();
  }
#pragma unroll
  for (int tm = 0; tm < 2; ++tm)
#pragma unroll
    for (int tn = 0; tn < 2; ++tn) {
      const int cl = wn + tn * 16 + fm;
      const int col = n0 + cl;
      const float bgv = bg[col];
#pragma unroll
      for (int r = 0; r < 4; ++r) {
        const int rl = wm + tm * 16 + quad * 4 + r;
        const int row = m0 + rl;
        const size_t off = (size_t)b * NN * DD + (size_t)row * DD + col;
        const float g = 1.f / (1.f + __expf(-(acc[tm][tn][r] + bgv)));
        const float cv = __uint_as_float(((uint32_t)Cbf[off]) << 16);
        const float o = g * Uf[off] + (1.f - g) * cv;
        Uout[off] = o;
        const ushort ob = f2bf(o);
        UbfOut[off] = ob;
        Tt[rl][cl] = ob;
      }
    }
  __syncthreads();
  // transposed bf16 write: UT[b][d][n]
#pragma unroll
  for (int p = 0; p < 4; ++p) {
    const int cl = (tid >> 4) + p * 16;
    const int rl = (tid & 15) * 4;
    ushort4 o;
    o.x = Tt[rl + 0][cl]; o.y = Tt[rl + 1][cl];
    o.z = Tt[rl + 2][cl]; o.w = Tt[rl + 3][cl];
    *(ushort4*)&UTOut[((size_t)b * DD + n0 + cl) * NN + m0 + rl] = o;
  }
}

// --------- output assembly: out = [cand copy | final update copy] ----------
__global__ __launch_bounds__(256) void out_copy(
    const float* __restrict__ cand, const float* __restrict__ upd,
    float* __restrict__ out) {
  const int t = blockIdx.x * 256 + threadIdx.x;
  float4* o4 = (float4*)out;
  if (t < 524288) o4[t] = ((const float4*)cand)[t];
  else o4[t] = ((const float4*)upd)[t - 524288];
}

// --------- scatter: cand_new[b, prune[b,i], :] = upd[b,i,:] for i < span_len[b] ---------
__global__ __launch_bounds__(128) void scatter_k(
    float* __restrict__ out_cand, const float* __restrict__ upd,
    const int* __restrict__ prune, const int* __restrict__ span_len) {
  const int row = blockIdx.x;
  const int b = row >> 10, i = row & 1023;
  if (i >= span_len[b]) return;
  const int dst = prune[row];
  const float4* src = (const float4*)(upd + (size_t)row * DD);
  float4* d = (float4*)(out_cand + ((size_t)b * MM + dst) * DD);
  d[threadIdx.x] = src[threadIdx.x];
}

extern "C" void kernel_launch(void* const* d_in, const int* in_sizes, int n_in,
                              void* d_out, int out_size, void* d_ws, size_t ws_size,
                              hipStream_t stream) {
  const float* update = (const float*)d_in[0];
  const float* mask = (const float*)d_in[1];
  const float* cand = (const float*)d_in[2];
  const int* span_begin = (const int*)d_in[3];
  const int* prune = (const int*)d_in[5];
  const int* span_len = (const int*)d_in[6];
  const float* Wl = (const float*)d_in[7];
  const float* Wr = (const float*)d_in[8];
  const float* b_h = (const float*)d_in[9];
  const float* dist_emb = (const float*)d_in[10];
  const float* v_out = (const float*)d_in[11];
  const float* Wg = (const float*)d_in[13];
  const float* b_gate = (const float*)d_in[14];

  char* w = (char*)d_ws;
  float* left = (float*)w;        w += (size_t)NB * NN * HH * 4;   // 512 KB
  ushort* right_bf = (ushort*)w;  w += (size_t)NB * NN * HH * 2;   // 256 KB
  ushort* probs_bf = (ushort*)w;  w += (size_t)NB * NN * NN * 2;   // 4 MB
  ushort* ctxt_bf = (ushort*)w;   w += (size_t)NB * NN * DD * 2;   // 2 MB
  float* upd1 = (float*)w;        w += (size_t)NB * NN * DD * 4;   // 4 MB
  float* upd2 = (float*)w;        w += (size_t)NB * NN * DD * 4;   // 4 MB
  ushort* Ubf0 = (ushort*)w;      w += (size_t)NB * NN * DD * 2;   // 2 MB
  ushort* Ubf1 = (ushort*)w;      w += (size_t)NB * NN * DD * 2;   // 2 MB
  ushort* UT = (ushort*)w;        w += (size_t)NB * NN * DD * 2;   // 2 MB
  ushort* WgT = (ushort*)w;       w += (size_t)2 * DD * DD * 2;    // 1 MB

  float* out = (float*)d_out;

  // Wg [1024][512] -> WgT bf16 [512][1024]; update -> Ubf0 + UT (once)
  conv_t<<<dim3(8, 16, 1), 256, 0, stream>>>(Wg, WgT, WgT, 2 * DD, DD, 0);
  conv_t<<<dim3(8, 16, NB), 256, 0, stream>>>(update, Ubf0, UT, NN, DD, 1);

  const float* Ucur = update;
  float* nexts[2] = {upd1, upd2};
  ushort* ubf_in[2] = {Ubf0, Ubf1};
  ushort* ubf_out[2] = {Ubf1, Ubf0};
  for (int it = 0; it < 2; ++it) {
    lr_kernel<<<256, 256, 0, stream>>>(Ucur, Wl, Wr, left, right_bf);
    score_softmax<<<dim3(NN / 4, NB), 256, 0, stream>>>(
        left, right_bf, span_begin, mask, dist_emb, b_h, v_out, probs_bf);
    gemm_ctxt_mfma<<<dim3(8, 16, NB), 256, 0, stream>>>(probs_bf, UT, ctxt_bf);
    gemm_gate_mfma<<<dim3(8, 16, NB), 256, 0, stream>>>(
        ubf_in[it], ctxt_bf, WgT, b_gate, Ucur, nexts[it], ubf_out[it], UT);
    Ucur = nexts[it];
  }
  out_copy<<<3072, 256, 0, stream>>>(cand, Ucur, out);
  scatter_k<<<NB * NN, 128, 0, stream>>>(out, Ucur, prune, span_len);
}